// Round 8
// baseline (168.364 us; speedup 1.0000x reference)
//
#include <hip/hip_runtime.h>
#include <hip/hip_bf16.h>

#define N_ROWS 32768
#define D_INP  256
#define NEXP   32
#define D_OUTP 256
#define TROWS  64
#define NTILES 1056   // 8 * 132; max tiles = 65536/64 + 32
#define GROWS  32     // gate rows per block

typedef __attribute__((ext_vector_type(4))) float f32x4;
typedef __attribute__((ext_vector_type(8))) short bf16x8;

__device__ inline unsigned short f2b(float f) {
    union { __hip_bfloat16 h; unsigned short u; } cv;
    cv.h = __float2bfloat16(f);
    return cv.u;
}
__device__ inline float b2f(unsigned short u) {
    union { unsigned v; float f; } c; c.v = ((unsigned)u) << 16; return c.f;
}

// ---------------------------------------------------------------------------
// Kernel 1: gate GEMM (fp32 LDS-tiled) + softmax + top-2 + stats + bf16 x-cast.
// 32 rows/block, grid 1024; LDS = 33.3K (gw) + 16.9K (x half-tile) -> 3 blk/CU.
// Thread (e4 = tid&7, rq = tid>>3): row rq, experts {e4+8n}.
// ---------------------------------------------------------------------------
__global__ __launch_bounds__(256) void gate_kernel(
    const float* __restrict__ x, const float* __restrict__ noise,
    const float* __restrict__ gw, const float* __restrict__ gb,
    unsigned short* __restrict__ xb, float* __restrict__ tkp,
    int* __restrict__ tki, float* __restrict__ esum, int* __restrict__ ecnt)
{
    __shared__ float gws[NEXP * 260];    // 33,280 B
    __shared__ float xs[GROWS * 132];    // 16,896 B
    __shared__ float lsum[NEXP];
    __shared__ int   lcnt[NEXP];

    int tid = threadIdx.x;
    int row0 = blockIdx.x * GROWS;

    // stage gw: 2048 float4, 8 per thread
    #pragma unroll
    for (int it = 0; it < 8; ++it) {
        int q = it * 256 + tid;
        int e = q >> 6;
        int k = (q & 63) * 4;
        float4 v = ((const float4*)gw)[q];
        *(float4*)&gws[e * 260 + k] = v;
    }
    if (tid < NEXP) { lsum[tid] = 0.f; lcnt[tid] = 0; }

    int e4 = tid & 7;
    int rq = tid >> 3;   // 0..31

    float acc[4] = {0.f, 0.f, 0.f, 0.f};

    for (int h = 0; h < 2; ++h) {
        int ko = h * 128;
        __syncthreads();
        // stage xs: 32 rows x 32 float4 = 1024, 4 per thread; fused bf16 cast
        #pragma unroll
        for (int it = 0; it < 4; ++it) {
            int idx = it * 256 + tid;
            int r = idx >> 5;
            int f = idx & 31;
            float4 v = *(const float4*)(x + (size_t)(row0 + r) * D_INP + ko + f * 4);
            *(float4*)&xs[r * 132 + f * 4] = v;
            unsigned short b[4] = { f2b(v.x), f2b(v.y), f2b(v.z), f2b(v.w) };
            *(ushort4*)(xb + (size_t)(row0 + r) * D_INP + ko + f * 4) = *(ushort4*)b;
        }
        __syncthreads();
        #pragma unroll 4
        for (int c = 0; c < 32; ++c) {
            float4 xv = *(float4*)&xs[rq * 132 + c * 4];
            float4 wv[4];
            #pragma unroll
            for (int n = 0; n < 4; n++)
                wv[n] = *(float4*)&gws[(e4 + 8 * n) * 260 + ko + c * 4];
            #pragma unroll
            for (int n = 0; n < 4; n++)
                acc[n] = fmaf(xv.x, wv[n].x,
                         fmaf(xv.y, wv[n].y,
                         fmaf(xv.z, wv[n].z,
                         fmaf(xv.w, wv[n].w, acc[n]))));
        }
    }

    {
        int R = row0 + rq;
        float l[4], p[4];
        #pragma unroll
        for (int n = 0; n < 4; n++) {
            int E = e4 + 8 * n;
            l[n] = acc[n] + gb[E] + 0.1f * noise[(size_t)R * NEXP + E];
        }
        float mx = fmaxf(fmaxf(l[0], l[1]), fmaxf(l[2], l[3]));
        #pragma unroll
        for (int s = 1; s < 8; s <<= 1) mx = fmaxf(mx, __shfl_xor(mx, s));
        float sum = 0.f;
        #pragma unroll
        for (int n = 0; n < 4; n++) { p[n] = expf(l[n] - mx); sum += p[n]; }
        #pragma unroll
        for (int s = 1; s < 8; s <<= 1) sum += __shfl_xor(sum, s);
        float inv = 1.f / sum;
        #pragma unroll
        for (int n = 0; n < 4; n++) p[n] *= inv;

        // top-1 (ties -> lower expert index)
        float bp = p[0]; int bi = e4;
        #pragma unroll
        for (int n = 1; n < 4; n++) if (p[n] > bp) { bp = p[n]; bi = e4 + 8 * n; }
        #pragma unroll
        for (int s = 1; s < 8; s <<= 1) {
            float op = __shfl_xor(bp, s); int oi = __shfl_xor(bi, s);
            if (op > bp || (op == bp && oi < bi)) { bp = op; bi = oi; }
        }
        // top-2
        float bp2 = -1.f; int bi2 = 0;
        #pragma unroll
        for (int n = 0; n < 4; n++) {
            int E = e4 + 8 * n;
            float q = (E == bi) ? -1.f : p[n];
            if (q > bp2 || (q == bp2 && E < bi2)) { bp2 = q; bi2 = E; }
        }
        #pragma unroll
        for (int s = 1; s < 8; s <<= 1) {
            float op = __shfl_xor(bp2, s); int oi = __shfl_xor(bi2, s);
            if (op > bp2 || (op == bp2 && oi < bi2)) { bp2 = op; bi2 = oi; }
        }
        if (e4 == 0) {
            tkp[R * 2] = bp;  tkp[R * 2 + 1] = bp2;
            tki[R * 2] = bi;  tki[R * 2 + 1] = bi2;
            atomicAdd(&lcnt[bi], 1); atomicAdd(&lcnt[bi2], 1);
        }
        #pragma unroll
        for (int n = 0; n < 4; n++) atomicAdd(&lsum[e4 + 8 * n], p[n]);
    }

    __syncthreads();
    if (tid < NEXP) {
        unsafeAtomicAdd(&esum[tid], lsum[tid]);
        atomicAdd(&ecnt[tid], lcnt[tid]);
    }
}

// ---------------------------------------------------------------------------
// Kernel 1b: experts_w fp32 -> bf16 FRAGMENT-ORDER transpose (standalone,
// full-chip occupancy streaming):
//   wbT[((e*4+q)*8+kk)*4+nn][lane=kg*16+lr] = W[e*256+q*64+nn*16+lr][kk*32+kg*8..+8]
// ---------------------------------------------------------------------------
__global__ __launch_bounds__(256) void wtrans_kernel(
    const float* __restrict__ ew, unsigned short* __restrict__ wbT)
{
    int fid = blockIdx.x * 256 + threadIdx.x;   // [0, 262144)
    int row = fid >> 5;        // W output-row (= out col), [0, 8192)
    int kc  = fid & 31;        // 8-wide k chunk
    const float4* s = (const float4*)(ew + (size_t)row * D_INP + kc * 8);
    float4 v0 = s[0], v1 = s[1];
    unsigned short t[8] = { f2b(v0.x), f2b(v0.y), f2b(v0.z), f2b(v0.w),
                            f2b(v1.x), f2b(v1.y), f2b(v1.z), f2b(v1.w) };
    int e  = row >> 8;
    int rr = row & 255;
    int q  = rr >> 6;
    int nn = (rr >> 4) & 3;
    int lr = rr & 15;
    int kk = kc >> 2;
    int kg = kc & 3;
    size_t off = ((((size_t)(e * 4 + q) * 8 + kk) * 4 + nn) * 64 + kg * 16 + lr) * 8;
    *(uint4*)(wbT + off) = *(uint4*)t;
}

// ---------------------------------------------------------------------------
// Kernel 2: scatter (row,slot) into per-expert lists; local scan of ecnt;
// block 0 computes load-balance loss. 32 blocks x 1024 threads.
// ---------------------------------------------------------------------------
__global__ __launch_bounds__(1024) void build_list_kernel(
    const int* __restrict__ tki, const float* __restrict__ esum,
    const int* __restrict__ ecnt, int* __restrict__ cursor0,
    int* __restrict__ list, float* __restrict__ loss_out)
{
    __shared__ int lcnt[NEXP], lbase[NEXP], s_offs[NEXP + 1];
    int tid = threadIdx.x;
    if (tid < NEXP) lcnt[tid] = 0;
    if (tid < 32) {
        int c = ecnt[tid];
        int ic = c;
        #pragma unroll
        for (int s = 1; s < 32; s <<= 1) {
            int a = __shfl_up(ic, s, 32);
            if (tid >= s) ic += a;
        }
        s_offs[tid + 1] = ic;
        if (tid == 0) s_offs[0] = 0;
    }
    __syncthreads();
    int r = blockIdx.x * 1024 + tid;
    int e0 = tki[r * 2], e1 = tki[r * 2 + 1];
    int p0 = atomicAdd(&lcnt[e0], 1);
    int p1 = atomicAdd(&lcnt[e1], 1);
    __syncthreads();
    if (tid < NEXP) lbase[tid] = s_offs[tid] + atomicAdd(&cursor0[tid], lcnt[tid]);
    __syncthreads();
    list[lbase[e0] + p0] = r * 2;
    list[lbase[e1] + p1] = r * 2 + 1;

    if (blockIdx.x == 0 && tid < 32) {
        float d = esum[tid] * (1.f / N_ROWS) - (1.f / NEXP);
        float v = d * d;
        #pragma unroll
        for (int s = 16; s > 0; s >>= 1) v += __shfl_xor(v, s, 32);
        if (tid == 0) *loss_out = v;
    }
}

// ---------------------------------------------------------------------------
// Kernel 3: grouped expert GEMM, 64 gathered rows x 256 cols per block.
// B from fragment-order wbT (contiguous 1KB/wave-instr, W read once/block).
// A in LDS (chunk-XOR swizzle). bf16 epilogue via reused LDS -> y0/y1.
// ---------------------------------------------------------------------------
__global__ __launch_bounds__(256) void moe_gemm_kernel(
    const unsigned short* __restrict__ xb, const unsigned short* __restrict__ wbT,
    const float* __restrict__ expb, const float* __restrict__ tkp,
    const int* __restrict__ list, const int* __restrict__ ecnt,
    unsigned short* __restrict__ y0, unsigned short* __restrict__ y1)
{
    __shared__ int s_offs[NEXP + 1], s_toff[NEXP + 1];
    __shared__ unsigned short xa[TROWS * 256];   // 32 KB, dual-use
    __shared__ int   srow[TROWS];
    __shared__ int   sslot[TROWS];
    __shared__ float sprob[TROWS];

    int tid = threadIdx.x;
    if (tid < 32) {
        int c = ecnt[tid];
        int ic = c, itc = (c + TROWS - 1) >> 6;
        #pragma unroll
        for (int s = 1; s < 32; s <<= 1) {
            int a  = __shfl_up(ic, s, 32);  if (tid >= s) ic += a;
            int b2 = __shfl_up(itc, s, 32); if (tid >= s) itc += b2;
        }
        s_offs[tid + 1] = ic; s_toff[tid + 1] = itc;
        if (tid == 0) { s_offs[0] = 0; s_toff[0] = 0; }
    }
    __syncthreads();

    // bijective XCD swizzle: NTILES = 8 * 132
    int b = (blockIdx.x & 7) * (NTILES / 8) + (blockIdx.x >> 3);
    if (b >= s_toff[NEXP]) return;   // uniform exit before any further barrier
    int e = 0;
    #pragma unroll
    for (int s = 16; s; s >>= 1)
        if (e + s <= 31 && s_toff[e + s] <= b) e += s;
    int m0 = s_offs[e] + (b - s_toff[e]) * TROWS;
    int nr = min(TROWS, s_offs[e + 1] - m0);

    if (tid < TROWS) {
        if (tid < nr) {
            int ent = list[m0 + tid];
            srow[tid]  = ent >> 1;
            sslot[tid] = ent & 1;
            sprob[tid] = tkp[ent];
        } else { srow[tid] = -1; sslot[tid] = 0; sprob[tid] = 0.f; }
    }
    __syncthreads();

    // stage A: 4 threads/row; 16B chunks (tid&3)+4i, chunk-XOR swizzled
    {
        int r_ = tid >> 2;
        int gr = srow[r_]; if (gr < 0) gr = 0;
        const uint4* src = (const uint4*)(xb + (size_t)gr * D_INP);
        uint4* dst = (uint4*)xa;
        int swz = r_ & 7;
        #pragma unroll
        for (int i = 0; i < 8; ++i) {
            int c = (tid & 3) + 4 * i;
            dst[r_ * 32 + (c ^ swz)] = src[c];
        }
    }
    __syncthreads();

    int wave = tid >> 6;
    int lane = tid & 63;
    int lr = lane & 15;
    int kg = lane >> 4;
    int n0 = wave * 64;
    int aswz = lr & 7;

    const unsigned short* wbase = wbT + (size_t)(e * 4 + wave) * 32 * 512;

    f32x4 acc[4][4];
    #pragma unroll
    for (int mm = 0; mm < 4; mm++)
        #pragma unroll
        for (int nn = 0; nn < 4; nn++)
            acc[mm][nn] = (f32x4){0.f, 0.f, 0.f, 0.f};

    #pragma unroll
    for (int kk = 0; kk < 8; kk++) {
        int chunk = kk * 4 + kg;
        bf16x8 a[4], bb[4];
        #pragma unroll
        for (int mm = 0; mm < 4; mm++)
            a[mm] = *(const bf16x8*)&xa[(mm * 16 + lr) * 256 + ((chunk ^ aswz) * 8)];
        #pragma unroll
        for (int nn = 0; nn < 4; nn++)
            bb[nn] = *(const bf16x8*)(wbase + (kk * 4 + nn) * 512 + lane * 8);
        #pragma unroll
        for (int mm = 0; mm < 4; mm++)
            #pragma unroll
            for (int nn = 0; nn < 4; nn++)
                acc[mm][nn] = __builtin_amdgcn_mfma_f32_16x16x32_bf16(a[mm], bb[nn], acc[mm][nn], 0, 0, 0);
    }
    __syncthreads();   // A reads done; reuse xa for bf16 output staging

    // epilogue: (acc + bias) * prob -> bf16 into xa[row][col]
    {
        float bias[4];
        #pragma unroll
        for (int nn = 0; nn < 4; nn++) bias[nn] = expb[e * 256 + n0 + nn * 16 + lr];
        #pragma unroll
        for (int mm = 0; mm < 4; mm++) {
            #pragma unroll
            for (int j = 0; j < 4; j++) {
                int lrow = mm * 16 + kg * 4 + j;
                float pp = sprob[lrow];
                #pragma unroll
                for (int nn = 0; nn < 4; nn++) {
                    float v = (acc[mm][nn][j] + bias[nn]) * pp;
                    xa[lrow * 256 + n0 + nn * 16 + lr] = f2b(v);
                }
            }
        }
    }
    __syncthreads();

    // store: 4 threads/row, contiguous 16B chunks of the 512B bf16 row
    {
        int r_ = tid >> 2;
        int gr = srow[r_];
        if (gr >= 0) {
            unsigned short* dstb = (sslot[r_] ? y1 : y0) + (size_t)gr * D_OUTP;
            const uint4* src = (const uint4*)(xa + r_ * 256);
            uint4* dst = (uint4*)dstb;
            #pragma unroll
            for (int i = 0; i < 8; ++i) {
                int c = (tid & 3) + 4 * i;
                dst[c] = src[c];
            }
        }
    }
}

// ---------------------------------------------------------------------------
// Kernel 4: out = f32(y0) + f32(y1), streaming
// ---------------------------------------------------------------------------
__global__ __launch_bounds__(256) void combine_kernel(
    const unsigned short* __restrict__ y0, const unsigned short* __restrict__ y1,
    float* __restrict__ out)
{
    size_t i = ((size_t)blockIdx.x * 256 + threadIdx.x) * 8;
    uint4 a = *(const uint4*)(y0 + i);
    uint4 b = *(const uint4*)(y1 + i);
    const unsigned short* ap = (const unsigned short*)&a;
    const unsigned short* bp = (const unsigned short*)&b;
    float4 o0, o1;
    o0.x = b2f(ap[0]) + b2f(bp[0]);
    o0.y = b2f(ap[1]) + b2f(bp[1]);
    o0.z = b2f(ap[2]) + b2f(bp[2]);
    o0.w = b2f(ap[3]) + b2f(bp[3]);
    o1.x = b2f(ap[4]) + b2f(bp[4]);
    o1.y = b2f(ap[5]) + b2f(bp[5]);
    o1.z = b2f(ap[6]) + b2f(bp[6]);
    o1.w = b2f(ap[7]) + b2f(bp[7]);
    *(float4*)(out + i)     = o0;
    *(float4*)(out + i + 4) = o1;
}

// ---------------------------------------------------------------------------
extern "C" void kernel_launch(void* const* d_in, const int* in_sizes, int n_in,
                              void* d_out, int out_size, void* d_ws, size_t ws_size,
                              hipStream_t stream)
{
    const float* x   = (const float*)d_in[0];
    const float* noi = (const float*)d_in[1];
    const float* gw  = (const float*)d_in[2];
    const float* gb  = (const float*)d_in[3];
    const float* ew  = (const float*)d_in[4];
    const float* eb  = (const float*)d_in[5];
    float* out = (float*)d_out;

    char* p = (char*)d_ws;
    unsigned short* xb  = (unsigned short*)p; p += (size_t)N_ROWS * D_INP * 2;
    unsigned short* wbT = (unsigned short*)p; p += (size_t)NEXP * D_OUTP * D_INP * 2;
    unsigned short* y0  = (unsigned short*)p; p += (size_t)N_ROWS * D_OUTP * 2;
    unsigned short* y1  = (unsigned short*)p; p += (size_t)N_ROWS * D_OUTP * 2;
    float* tkp  = (float*)p; p += (size_t)N_ROWS * 2 * 4;
    int*   tki  = (int*)p;   p += (size_t)N_ROWS * 2 * 4;
    int*   list = (int*)p;   p += (size_t)N_ROWS * 2 * 4;
    float* esum = (float*)p; p += 32 * 4;
    int*   ecnt = (int*)p;   p += 32 * 4;
    int*   cur0 = (int*)p;   p += 32 * 4;

    hipMemsetAsync(esum, 0, 3 * 32 * 4, stream);   // esum + ecnt + cursor0

    gate_kernel<<<N_ROWS / GROWS, 256, 0, stream>>>(x, noi, gw, gb, xb, tkp, tki, esum, ecnt);
    wtrans_kernel<<<1024, 256, 0, stream>>>(ew, wbT);
    build_list_kernel<<<N_ROWS / 1024, 1024, 0, stream>>>(tki, esum, ecnt, cur0, list, out + (size_t)N_ROWS * D_OUTP);
    moe_gemm_kernel<<<NTILES, 256, 0, stream>>>(xb, wbT, eb, tkp, list, ecnt, y0, y1);
    combine_kernel<<<N_ROWS * D_OUTP / 8 / 256, 256, 0, stream>>>(y0, y1, out);
}

// Round 9
// 149.125 us; speedup vs baseline: 1.1290x; 1.1290x over previous
//
#include <hip/hip_runtime.h>
#include <hip/hip_bf16.h>

#define N_ROWS 32768
#define D_INP  256
#define NEXP   32
#define D_OUTP 256
#define TROWS  64
#define NTILES 1056   // 8 * 132; max tiles = 65536/64 + 32
#define GROWS  64     // gate rows per block

typedef __attribute__((ext_vector_type(4))) float f32x4;
typedef __attribute__((ext_vector_type(8))) short bf16x8;

__device__ inline unsigned short f2b(float f) {
    union { __hip_bfloat16 h; unsigned short u; } cv;
    cv.h = __float2bfloat16(f);
    return cv.u;
}
__device__ inline float b2f(unsigned short u) {
    union { unsigned v; float f; } c; c.v = ((unsigned)u) << 16; return c.f;
}

// ---------------------------------------------------------------------------
// Kernel 1: gate GEMM, register-blocked: thread = (e4=lane&7, rq=lane>>3),
// wave wid owns a 16-wide k-slice per 64-k stage; acc[8 rows][4 experts].
// LDS-read traffic: 768 lane-b128/row (was 2560). Partials reduced through
// LDS (aliased over dead gw tile, stride-33 pad). Softmax/top-2 in 4-lane
// teams. Fused: bf16 x-cast (during staging) + experts_w fragment-order
// transpose (tail). 64 rows/block, grid 512, 51.5KB LDS -> 3 blk/CU.
// ---------------------------------------------------------------------------
__global__ __launch_bounds__(256) void gate_kernel(
    const float* __restrict__ x, const float* __restrict__ noise,
    const float* __restrict__ gw, const float* __restrict__ gb,
    const float* __restrict__ ew, unsigned short* __restrict__ wbT,
    unsigned short* __restrict__ xb, float* __restrict__ tkp,
    int* __restrict__ tki, float* __restrict__ esum, int* __restrict__ ecnt)
{
    __shared__ float rA[8448];        // gws[32][260]=8320f, then red[4][64][33]=8448f
    __shared__ float xs[64 * 68];     // current 64-k stage of x, pad 68
    __shared__ float lsum[NEXP];
    __shared__ int   lcnt[NEXP];

    int tid = threadIdx.x;
    int row0 = blockIdx.x * GROWS;

    // stage gw: 2048 float4, 8 per thread
    #pragma unroll
    for (int it = 0; it < 8; ++it) {
        int q = it * 256 + tid;
        int e = q >> 6;
        int k = (q & 63) * 4;
        float4 v = ((const float4*)gw)[q];
        *(float4*)&rA[e * 260 + k] = v;
    }
    if (tid < NEXP) { lsum[tid] = 0.f; lcnt[tid] = 0; }

    int lane = tid & 63;
    int wid  = tid >> 6;     // k-slice owner
    int e4 = lane & 7;
    int rq = lane >> 3;      // 0..7

    float acc[8][4];
    #pragma unroll
    for (int m = 0; m < 8; m++)
        #pragma unroll
        for (int n = 0; n < 4; n++) acc[m][n] = 0.f;

    for (int s = 0; s < 4; ++s) {
        __syncthreads();   // s=0: gw staged; s>0: previous compute done
        // stage xs: 64 rows x 64 k = 1024 float4, 4/thread; fused bf16 cast
        #pragma unroll
        for (int it = 0; it < 4; ++it) {
            int q = it * 256 + tid;
            int r = q >> 4;
            int kq = q & 15;
            float4 v = *(const float4*)(x + (size_t)(row0 + r) * D_INP + s * 64 + kq * 4);
            *(float4*)&xs[r * 68 + kq * 4] = v;
            unsigned short b[4] = { f2b(v.x), f2b(v.y), f2b(v.z), f2b(v.w) };
            *(ushort4*)(xb + (size_t)(row0 + r) * D_INP + s * 64 + kq * 4) = *(ushort4*)b;
        }
        __syncthreads();
        int ko = s * 64 + wid * 16;   // this wave's k-slice (global k)
        #pragma unroll
        for (int c = 0; c < 4; ++c) {
            float4 wv[4];
            #pragma unroll
            for (int n = 0; n < 4; n++)
                wv[n] = *(float4*)&rA[(e4 + 8 * n) * 260 + ko + c * 4];
            #pragma unroll
            for (int m = 0; m < 8; m++) {
                float4 xv = *(float4*)&xs[(rq + 8 * m) * 68 + wid * 16 + c * 4];
                #pragma unroll
                for (int n = 0; n < 4; n++)
                    acc[m][n] = fmaf(xv.x, wv[n].x,
                                fmaf(xv.y, wv[n].y,
                                fmaf(xv.z, wv[n].z,
                                fmaf(xv.w, wv[n].w, acc[m][n]))));
            }
        }
    }
    __syncthreads();   // compute done; gw region dead -> reuse as red

    // write partials: red[wid][lane][m*4+n], stride 33 (conflict-free)
    {
        int base = (wid * 64 + lane) * 33;
        #pragma unroll
        for (int m = 0; m < 8; m++)
            #pragma unroll
            for (int n = 0; n < 4; n++)
                rA[base + m * 4 + n] = acc[m][n];
    }
    __syncthreads();

    // reduce 4 partials + softmax + top-2; thread t: row=t>>2, experts eo..eo+7
    {
        int row = tid >> 2;
        int eo  = (tid & 3) * 8;
        int n   = tid & 3;           // = eo>>3
        int R = row0 + row;
        int j = (row >> 3) * 4 + n;  // writer's m*4+n
        int lpb = (row & 7) * 8;     // writer lane' base
        float4 nz0 = *(const float4*)(noise + (size_t)R * NEXP + eo);
        float4 nz1 = *(const float4*)(noise + (size_t)R * NEXP + eo + 4);
        float nz[8] = { nz0.x, nz0.y, nz0.z, nz0.w, nz1.x, nz1.y, nz1.z, nz1.w };
        float l[8], p[8];
        #pragma unroll
        for (int i = 0; i < 8; i++) {
            int a = (lpb + i) * 33 + j;
            float v = rA[a] + rA[2112 + a] + rA[4224 + a] + rA[6336 + a];
            l[i] = v + gb[eo + i] + 0.1f * nz[i];
        }
        float mx = l[0];
        #pragma unroll
        for (int i = 1; i < 8; i++) mx = fmaxf(mx, l[i]);
        mx = fmaxf(mx, __shfl_xor(mx, 1));
        mx = fmaxf(mx, __shfl_xor(mx, 2));
        float sum = 0.f;
        #pragma unroll
        for (int i = 0; i < 8; i++) { p[i] = expf(l[i] - mx); sum += p[i]; }
        sum += __shfl_xor(sum, 1);
        sum += __shfl_xor(sum, 2);
        float inv = 1.f / sum;
        #pragma unroll
        for (int i = 0; i < 8; i++) p[i] *= inv;

        // top-1 (ties -> lower expert index; ascending scan keeps lower)
        float bp = p[0]; int bi = eo;
        #pragma unroll
        for (int i = 1; i < 8; i++) if (p[i] > bp) { bp = p[i]; bi = eo + i; }
        #pragma unroll
        for (int s2 = 1; s2 < 4; s2 <<= 1) {
            float op = __shfl_xor(bp, s2); int oi = __shfl_xor(bi, s2);
            if (op > bp || (op == bp && oi < bi)) { bp = op; bi = oi; }
        }
        // top-2
        float bp2 = -1.f; int bi2 = 0;
        #pragma unroll
        for (int i = 0; i < 8; i++) {
            int E = eo + i;
            float q = (E == bi) ? -1.f : p[i];
            if (q > bp2 || (q == bp2 && E < bi2)) { bp2 = q; bi2 = E; }
        }
        #pragma unroll
        for (int s2 = 1; s2 < 4; s2 <<= 1) {
            float op = __shfl_xor(bp2, s2); int oi = __shfl_xor(bi2, s2);
            if (op > bp2 || (op == bp2 && oi < bi2)) { bp2 = op; bi2 = oi; }
        }
        if ((tid & 3) == 0) {
            tkp[R * 2] = bp;  tkp[R * 2 + 1] = bp2;
            tki[R * 2] = bi;  tki[R * 2 + 1] = bi2;
            atomicAdd(&lcnt[bi], 1); atomicAdd(&lcnt[bi2], 1);
        }
        #pragma unroll
        for (int i = 0; i < 8; i++) atomicAdd(&lsum[eo + i], p[i]);
    }

    // fused experts_w fragment transpose: 2 fragments/thread (512 blocks)
    #pragma unroll
    for (int it = 0; it < 2; ++it) {
        int fid = blockIdx.x * 512 + it * 256 + tid;
        int row = fid >> 5;
        int kc  = fid & 31;
        const float4* sp = (const float4*)(ew + (size_t)row * D_INP + kc * 8);
        float4 v0 = sp[0], v1 = sp[1];
        unsigned short t[8] = { f2b(v0.x), f2b(v0.y), f2b(v0.z), f2b(v0.w),
                                f2b(v1.x), f2b(v1.y), f2b(v1.z), f2b(v1.w) };
        int e  = row >> 8;
        int rr = row & 255;
        int q  = rr >> 6;
        int nn = (rr >> 4) & 3;
        int lr = rr & 15;
        int kk = kc >> 2;
        int kg = kc & 3;
        size_t off = ((((size_t)(e * 4 + q) * 8 + kk) * 4 + nn) * 64 + kg * 16 + lr) * 8;
        *(uint4*)(wbT + off) = *(uint4*)t;
    }

    __syncthreads();
    if (tid < NEXP) {
        unsafeAtomicAdd(&esum[tid], lsum[tid]);
        atomicAdd(&ecnt[tid], lcnt[tid]);
    }
}

// ---------------------------------------------------------------------------
// Kernel 2: scatter (row,slot) into per-expert lists; local scan of ecnt;
// block 0 computes load-balance loss. 32 blocks x 1024 threads.
// ---------------------------------------------------------------------------
__global__ __launch_bounds__(1024) void build_list_kernel(
    const int* __restrict__ tki, const float* __restrict__ esum,
    const int* __restrict__ ecnt, int* __restrict__ cursor0,
    int* __restrict__ list, float* __restrict__ loss_out)
{
    __shared__ int lcnt[NEXP], lbase[NEXP], s_offs[NEXP + 1];
    int tid = threadIdx.x;
    if (tid < NEXP) lcnt[tid] = 0;
    if (tid < 32) {
        int c = ecnt[tid];
        int ic = c;
        #pragma unroll
        for (int s = 1; s < 32; s <<= 1) {
            int a = __shfl_up(ic, s, 32);
            if (tid >= s) ic += a;
        }
        s_offs[tid + 1] = ic;
        if (tid == 0) s_offs[0] = 0;
    }
    __syncthreads();
    int r = blockIdx.x * 1024 + tid;
    int e0 = tki[r * 2], e1 = tki[r * 2 + 1];
    int p0 = atomicAdd(&lcnt[e0], 1);
    int p1 = atomicAdd(&lcnt[e1], 1);
    __syncthreads();
    if (tid < NEXP) lbase[tid] = s_offs[tid] + atomicAdd(&cursor0[tid], lcnt[tid]);
    __syncthreads();
    list[lbase[e0] + p0] = r * 2;
    list[lbase[e1] + p1] = r * 2 + 1;

    if (blockIdx.x == 0 && tid < 32) {
        float d = esum[tid] * (1.f / N_ROWS) - (1.f / NEXP);
        float v = d * d;
        #pragma unroll
        for (int s = 16; s > 0; s >>= 1) v += __shfl_xor(v, s, 32);
        if (tid == 0) *loss_out = v;
    }
}

// ---------------------------------------------------------------------------
// Kernel 3: grouped expert GEMM, 64 gathered rows x 256 cols per block.
// B from fragment-order wbT (contiguous 1KB/wave-instr, W read once/block).
// A in LDS (chunk-XOR swizzle). bf16 epilogue via reused LDS -> y0/y1.
// ---------------------------------------------------------------------------
__global__ __launch_bounds__(256) void moe_gemm_kernel(
    const unsigned short* __restrict__ xb, const unsigned short* __restrict__ wbT,
    const float* __restrict__ expb, const float* __restrict__ tkp,
    const int* __restrict__ list, const int* __restrict__ ecnt,
    unsigned short* __restrict__ y0, unsigned short* __restrict__ y1)
{
    __shared__ int s_offs[NEXP + 1], s_toff[NEXP + 1];
    __shared__ unsigned short xa[TROWS * 256];   // 32 KB, dual-use
    __shared__ int   srow[TROWS];
    __shared__ int   sslot[TROWS];
    __shared__ float sprob[TROWS];

    int tid = threadIdx.x;
    if (tid < 32) {
        int c = ecnt[tid];
        int ic = c, itc = (c + TROWS - 1) >> 6;
        #pragma unroll
        for (int s = 1; s < 32; s <<= 1) {
            int a  = __shfl_up(ic, s, 32);  if (tid >= s) ic += a;
            int b2 = __shfl_up(itc, s, 32); if (tid >= s) itc += b2;
        }
        s_offs[tid + 1] = ic; s_toff[tid + 1] = itc;
        if (tid == 0) { s_offs[0] = 0; s_toff[0] = 0; }
    }
    __syncthreads();

    // bijective XCD swizzle: NTILES = 8 * 132
    int b = (blockIdx.x & 7) * (NTILES / 8) + (blockIdx.x >> 3);
    if (b >= s_toff[NEXP]) return;   // uniform exit before any further barrier
    int e = 0;
    #pragma unroll
    for (int s = 16; s; s >>= 1)
        if (e + s <= 31 && s_toff[e + s] <= b) e += s;
    int m0 = s_offs[e] + (b - s_toff[e]) * TROWS;
    int nr = min(TROWS, s_offs[e + 1] - m0);

    if (tid < TROWS) {
        if (tid < nr) {
            int ent = list[m0 + tid];
            srow[tid]  = ent >> 1;
            sslot[tid] = ent & 1;
            sprob[tid] = tkp[ent];
        } else { srow[tid] = -1; sslot[tid] = 0; sprob[tid] = 0.f; }
    }
    __syncthreads();

    // stage A: 4 threads/row; 16B chunks (tid&3)+4i, chunk-XOR swizzled
    {
        int r_ = tid >> 2;
        int gr = srow[r_]; if (gr < 0) gr = 0;
        const uint4* src = (const uint4*)(xb + (size_t)gr * D_INP);
        uint4* dst = (uint4*)xa;
        int swz = r_ & 7;
        #pragma unroll
        for (int i = 0; i < 8; ++i) {
            int c = (tid & 3) + 4 * i;
            dst[r_ * 32 + (c ^ swz)] = src[c];
        }
    }
    __syncthreads();

    int wave = tid >> 6;
    int lane = tid & 63;
    int lr = lane & 15;
    int kg = lane >> 4;
    int n0 = wave * 64;
    int aswz = lr & 7;

    const unsigned short* wbase = wbT + (size_t)(e * 4 + wave) * 32 * 512;

    f32x4 acc[4][4];
    #pragma unroll
    for (int mm = 0; mm < 4; mm++)
        #pragma unroll
        for (int nn = 0; nn < 4; nn++)
            acc[mm][nn] = (f32x4){0.f, 0.f, 0.f, 0.f};

    #pragma unroll
    for (int kk = 0; kk < 8; kk++) {
        int chunk = kk * 4 + kg;
        bf16x8 a[4], bb[4];
        #pragma unroll
        for (int mm = 0; mm < 4; mm++)
            a[mm] = *(const bf16x8*)&xa[(mm * 16 + lr) * 256 + ((chunk ^ aswz) * 8)];
        #pragma unroll
        for (int nn = 0; nn < 4; nn++)
            bb[nn] = *(const bf16x8*)(wbase + (kk * 4 + nn) * 512 + lane * 8);
        #pragma unroll
        for (int mm = 0; mm < 4; mm++)
            #pragma unroll
            for (int nn = 0; nn < 4; nn++)
                acc[mm][nn] = __builtin_amdgcn_mfma_f32_16x16x32_bf16(a[mm], bb[nn], acc[mm][nn], 0, 0, 0);
    }
    __syncthreads();   // A reads done; reuse xa for bf16 output staging

    // epilogue: (acc + bias) * prob -> bf16 into xa[row][col]
    {
        float bias[4];
        #pragma unroll
        for (int nn = 0; nn < 4; nn++) bias[nn] = expb[e * 256 + n0 + nn * 16 + lr];
        #pragma unroll
        for (int mm = 0; mm < 4; mm++) {
            #pragma unroll
            for (int j = 0; j < 4; j++) {
                int lrow = mm * 16 + kg * 4 + j;
                float pp = sprob[lrow];
                #pragma unroll
                for (int nn = 0; nn < 4; nn++) {
                    float v = (acc[mm][nn][j] + bias[nn]) * pp;
                    xa[lrow * 256 + n0 + nn * 16 + lr] = f2b(v);
                }
            }
        }
    }
    __syncthreads();

    // store: 4 threads/row, contiguous 16B chunks of the 512B bf16 row
    {
        int r_ = tid >> 2;
        int gr = srow[r_];
        if (gr >= 0) {
            unsigned short* dstb = (sslot[r_] ? y1 : y0) + (size_t)gr * D_OUTP;
            const uint4* src = (const uint4*)(xa + r_ * 256);
            uint4* dst = (uint4*)dstb;
            #pragma unroll
            for (int i = 0; i < 8; ++i) {
                int c = (tid & 3) + 4 * i;
                dst[c] = src[c];
            }
        }
    }
}

// ---------------------------------------------------------------------------
// Kernel 4: out = f32(y0) + f32(y1), streaming
// ---------------------------------------------------------------------------
__global__ __launch_bounds__(256) void combine_kernel(
    const unsigned short* __restrict__ y0, const unsigned short* __restrict__ y1,
    float* __restrict__ out)
{
    size_t i = ((size_t)blockIdx.x * 256 + threadIdx.x) * 8;
    uint4 a = *(const uint4*)(y0 + i);
    uint4 b = *(const uint4*)(y1 + i);
    const unsigned short* ap = (const unsigned short*)&a;
    const unsigned short* bp = (const unsigned short*)&b;
    float4 o0, o1;
    o0.x = b2f(ap[0]) + b2f(bp[0]);
    o0.y = b2f(ap[1]) + b2f(bp[1]);
    o0.z = b2f(ap[2]) + b2f(bp[2]);
    o0.w = b2f(ap[3]) + b2f(bp[3]);
    o1.x = b2f(ap[4]) + b2f(bp[4]);
    o1.y = b2f(ap[5]) + b2f(bp[5]);
    o1.z = b2f(ap[6]) + b2f(bp[6]);
    o1.w = b2f(ap[7]) + b2f(bp[7]);
    *(float4*)(out + i)     = o0;
    *(float4*)(out + i + 4) = o1;
}

// ---------------------------------------------------------------------------
extern "C" void kernel_launch(void* const* d_in, const int* in_sizes, int n_in,
                              void* d_out, int out_size, void* d_ws, size_t ws_size,
                              hipStream_t stream)
{
    const float* x   = (const float*)d_in[0];
    const float* noi = (const float*)d_in[1];
    const float* gw  = (const float*)d_in[2];
    const float* gb  = (const float*)d_in[3];
    const float* ew  = (const float*)d_in[4];
    const float* eb  = (const float*)d_in[5];
    float* out = (float*)d_out;

    char* p = (char*)d_ws;
    unsigned short* xb  = (unsigned short*)p; p += (size_t)N_ROWS * D_INP * 2;
    unsigned short* wbT = (unsigned short*)p; p += (size_t)NEXP * D_OUTP * D_INP * 2;
    unsigned short* y0  = (unsigned short*)p; p += (size_t)N_ROWS * D_OUTP * 2;
    unsigned short* y1  = (unsigned short*)p; p += (size_t)N_ROWS * D_OUTP * 2;
    float* tkp  = (float*)p; p += (size_t)N_ROWS * 2 * 4;
    int*   tki  = (int*)p;   p += (size_t)N_ROWS * 2 * 4;
    int*   list = (int*)p;   p += (size_t)N_ROWS * 2 * 4;
    float* esum = (float*)p; p += 32 * 4;
    int*   ecnt = (int*)p;   p += 32 * 4;
    int*   cur0 = (int*)p;   p += 32 * 4;

    hipMemsetAsync(esum, 0, 3 * 32 * 4, stream);   // esum + ecnt + cursor0

    gate_kernel<<<N_ROWS / GROWS, 256, 0, stream>>>(x, noi, gw, gb, ew, wbT, xb, tkp, tki, esum, ecnt);
    build_list_kernel<<<N_ROWS / 1024, 1024, 0, stream>>>(tki, esum, ecnt, cur0, list, out + (size_t)N_ROWS * D_OUTP);
    moe_gemm_kernel<<<NTILES, 256, 0, stream>>>(xb, wbT, eb, tkp, list, ecnt, y0, y1);
    combine_kernel<<<N_ROWS * D_OUTP / 8 / 256, 256, 0, stream>>>(y0, y1, out);
}